// Round 1
// baseline (291.045 us; speedup 1.0000x reference)
//
#include <hip/hip_runtime.h>
#include <hip/hip_bf16.h>

// MHA: B=4 L=2048 D=1024 H=16 DH=64, causal. Inputs f32 (sniffed; dtype-proof).
// Round 8: VALU diet for attn_k (it was VALU-bound: 59.7% VALUBusy vs 17.4% MfmaUtil):
//  - exp2 domain: log2(e) folded into Q scale -> bare v_exp_f32, no per-elem mul
//  - row-sum via MFMA ones-column (o_sum) -> no 16 adds + 2 shfl/tile, no l_run,
//    shuffle-free epilogue (o_sum C-layout row==quad*4+r matches o_acc)
//  - defer-max (THR=8, log2 domain): skip alpha rescale pass when max doesn't grow
//  - max3-friendly tile-max reduction
// Memory structure unchanged from R7 (S^T attention, swizzled LDS, fused QKV GEMM).

typedef __bf16 bf16;
typedef __bf16 bf16x4 __attribute__((ext_vector_type(4)));
typedef __bf16 bf16x8 __attribute__((ext_vector_type(8)));
typedef float f32x4 __attribute__((ext_vector_type(4)));

#define DEV static __device__ __forceinline__

constexpr int B = 4, L = 2048, D = 1024, H = 16, DH = 64;
constexpr int BL = B * L;                      // 8192
constexpr int GM = 8192, GK = 1024;
constexpr int BKg = 64;                        // GEMM K-tile
constexpr int PST = 72;                        // padded P row stride (elements)

typedef __attribute__((address_space(1))) const void* gptr1;
typedef __attribute__((address_space(3))) void* lptr3;

DEV void load_lds16(const bf16* g, bf16* l) {
  __builtin_amdgcn_global_load_lds((gptr1)g, (lptr3)l, 16, 0, 0);
}

DEV f32x4 mfma(bf16x8 a, bf16x8 b, f32x4 c) {
  return __builtin_amdgcn_mfma_f32_16x16x32_bf16(a, b, c, 0, 0, 0);
}

DEV float scrub(float v) { return (v == v) ? v : 0.f; }

// ---------- dtype sniff (flag=1: bf16 storage, 0: f32) ----------
__global__ void sniff_k(const unsigned short* __restrict__ xr, int* flag) {
  __shared__ int cnt;
  if (threadIdx.x == 0) cnt = 0;
  __syncthreads();
  int local = 0;
  for (int i = threadIdx.x; i < 4096; i += 64) {
    const unsigned short u = xr[2 * i];
    const int e = (u >> 7) & 0xFF;
    if (e >= 0x70 && e <= 0x85) local++;
  }
  atomicAdd(&cnt, local);
  __syncthreads();
  if (threadIdx.x == 0) *flag = (cnt > 2048) ? 1 : 0;
}

// ---------- canonicalize x -> bf16 ----------
__global__ __launch_bounds__(256) void cvt_x_k(const void* __restrict__ src,
                                               bf16* __restrict__ dst,
                                               const int* __restrict__ flag, int n) {
  const bool isbf = (*flag != 0);
  const int stride = gridDim.x * blockDim.x * 8;
  for (int idx = (blockIdx.x * blockDim.x + threadIdx.x) * 8; idx < n; idx += stride) {
    bf16x8 o;
    if (isbf) {
      bf16x8 v = *(const bf16x8*)((const bf16*)src + idx);
      #pragma unroll
      for (int j = 0; j < 8; ++j) o[j] = (bf16)scrub((float)v[j]);
    } else {
      const float* s = (const float*)src + idx;
      #pragma unroll
      for (int j = 0; j < 8; ++j) o[j] = (bf16)scrub(s[j]);
    }
    *(bf16x8*)&dst[idx] = o;
  }
}

// ---------- 4-way transpose+canonicalize: dstz[n][k] = srcz[k][n] ----------
__global__ __launch_bounds__(256) void wtrans_cvt4_k(const void* __restrict__ W0,
                                                     const void* __restrict__ W1,
                                                     const void* __restrict__ W2,
                                                     const void* __restrict__ W3,
                                                     bf16* __restrict__ dstBase,
                                                     const int* __restrict__ flag) {
  __shared__ bf16 t[32][33];
  const bool isbf = (*flag != 0);
  const int z = blockIdx.z;
  const void* src = (z == 0) ? W0 : (z == 1) ? W1 : (z == 2) ? W2 : W3;
  bf16* dst = dstBase + (size_t)z * D * D;
  const int bx = blockIdx.x * 32, by = blockIdx.y * 32;
  const int tx = threadIdx.x & 31, ty = threadIdx.x >> 5;
  for (int i = ty; i < 32; i += 8) {
    const size_t off = (size_t)(by + i) * D + bx + tx;
    const float v = isbf ? (float)((const bf16*)src)[off] : ((const float*)src)[off];
    t[i][tx] = (bf16)scrub(v);
  }
  __syncthreads();
  for (int i = ty; i < 32; i += 8)
    dst[(size_t)(bx + i) * D + by + tx] = t[tx][i];
}

// ---------- per-head V transpose: VT[bh][d][l] = V[(b,l)][h*64+d] ----------
__global__ __launch_bounds__(256) void vtrans_k(const bf16* __restrict__ V,
                                                bf16* __restrict__ VT) {
  __shared__ __align__(16) bf16 t[64 * 72];
  const int l0 = blockIdx.x * 64, bh = blockIdx.y;
  const int b = bh >> 4, h = bh & 15;
  const int tid = threadIdx.x;
  #pragma unroll
  for (int i = 0; i < 2; ++i) {
    const int o = tid * 8 + i * 2048;
    const int lrow = o >> 6, dcol = o & 63;
    *(bf16x8*)&t[lrow * 72 + dcol] =
        *(const bf16x8*)&V[(size_t)(b * L + l0 + lrow) * D + h * 64 + dcol];
  }
  __syncthreads();
  const int d = tid >> 2, lg = (tid & 3) * 16;
  bf16x8 o0, o1;
  #pragma unroll
  for (int j = 0; j < 8; ++j) o0[j] = t[(lg + j) * 72 + d];
  #pragma unroll
  for (int j = 0; j < 8; ++j) o1[j] = t[(lg + 8 + j) * 72 + d];
  bf16* dst = VT + ((size_t)bh * DH + d) * L + l0 + lg;
  *(bf16x8*)dst = o0;
  *(bf16x8*)(dst + 8) = o1;
}

// ---------- fused QKV GEMM: [Q|K|V] = x @ [WqT|WkT|WvT]^T + b ----------
// Bt is the stacked [3072][1024] weight; buffer selected by n0>>10 (uniform).
// Q epilogue folds 1/sqrt(DH) * log2(e) = 0.125*1.4426950 (exp2-domain softmax).
__global__ __launch_bounds__(256) void qkv_gemm_k(const bf16* __restrict__ A,
                                                  const bf16* __restrict__ Bt,
                                                  const void* __restrict__ bq,
                                                  const void* __restrict__ bk,
                                                  const void* __restrict__ bv,
                                                  bf16* __restrict__ Q,
                                                  bf16* __restrict__ Kk,
                                                  bf16* __restrict__ V,
                                                  const int* __restrict__ flag) {
  __shared__ __align__(16) bf16 As[128 * BKg];
  __shared__ __align__(16) bf16 Bs[128 * BKg];
  const bool isbf = (*flag != 0);
  const int m0 = blockIdx.x * 128, n0 = blockIdx.y * 128;
  const int buf = n0 >> 10, nloc = n0 & 1023;
  bf16* Cb = (buf == 0) ? Q : (buf == 1) ? Kk : V;
  const void* bias = (buf == 0) ? bq : (buf == 1) ? bk : bv;
  const float scale = (buf == 0) ? 0.18033688011111f : 1.0f; // 0.125*log2(e)

  const int tid = threadIdx.x, wave = tid >> 6, lane = tid & 63;
  const int wr = wave >> 1, wc = wave & 1;
  const int quad = lane >> 4, l16 = lane & 15;
  const int srow = lane >> 3;
  const int scol = ((lane ^ srow) & 7) * 8;
  const int l7 = l16 & 7;
  const int s0 = ((quad ^ l7) * 8);
  const int s1 = s0 ^ 32;

  f32x4 acc[4][4] = {};

  for (int k0 = 0; k0 < GK; k0 += BKg) {
    for (int c = wave; c < 16; c += 4) {
      load_lds16(A  + (size_t)(m0 + c * 8 + srow) * GK + k0 + scol, &As[c * 512]);
      load_lds16(Bt + (size_t)(n0 + c * 8 + srow) * GK + k0 + scol, &Bs[c * 512]);
    }
    __syncthreads();
    #pragma unroll
    for (int kk = 0; kk < BKg; kk += 32) {
      const int sk = kk ? s1 : s0;
      bf16x8 af[4], bfr[4];
      #pragma unroll
      for (int i = 0; i < 4; ++i)
        af[i] = *(const bf16x8*)&As[(wr * 64 + i * 16 + l16) * BKg + sk];
      #pragma unroll
      for (int i = 0; i < 4; ++i)
        bfr[i] = *(const bf16x8*)&Bs[(wc * 64 + i * 16 + l16) * BKg + sk];
      #pragma unroll
      for (int mi = 0; mi < 4; ++mi)
        #pragma unroll
        for (int ni = 0; ni < 4; ++ni)
          acc[mi][ni] = mfma(af[mi], bfr[ni], acc[mi][ni]);
    }
    __syncthreads();
  }

  #pragma unroll
  for (int ni = 0; ni < 4; ++ni) {
    const int col = nloc + wc * 64 + ni * 16 + l16;
    const float bv2 = isbf ? (float)((const bf16*)bias)[col] : ((const float*)bias)[col];
    #pragma unroll
    for (int mi = 0; mi < 4; ++mi)
      #pragma unroll
      for (int r = 0; r < 4; ++r) {
        const int row = m0 + wr * 64 + mi * 16 + quad * 4 + r;
        Cb[(size_t)row * D + col] = (bf16)((acc[mi][ni][r] + bv2) * scale);
      }
  }
}

// ---------- final GEMM: out = attnO @ WoT^T + bo (dtype per flag) ----------
__global__ __launch_bounds__(256) void gemm_bt_k(const bf16* __restrict__ A,
                                                 const bf16* __restrict__ Bt,
                                                 const void* __restrict__ bias,
                                                 void* __restrict__ C,
                                                 const int* __restrict__ flag) {
  __shared__ __align__(16) bf16 As[128 * BKg];
  __shared__ __align__(16) bf16 Bs[128 * BKg];
  const bool isbf = (*flag != 0);
  const int m0 = blockIdx.x * 128, n0 = blockIdx.y * 128;
  const int tid = threadIdx.x, wave = tid >> 6, lane = tid & 63;
  const int wr = wave >> 1, wc = wave & 1;
  const int quad = lane >> 4, l16 = lane & 15;
  const int srow = lane >> 3;
  const int scol = ((lane ^ srow) & 7) * 8;
  const int l7 = l16 & 7;
  const int s0 = ((quad ^ l7) * 8);
  const int s1 = s0 ^ 32;

  f32x4 acc[4][4] = {};

  for (int k0 = 0; k0 < GK; k0 += BKg) {
    for (int c = wave; c < 16; c += 4) {
      load_lds16(A  + (size_t)(m0 + c * 8 + srow) * GK + k0 + scol, &As[c * 512]);
      load_lds16(Bt + (size_t)(n0 + c * 8 + srow) * GK + k0 + scol, &Bs[c * 512]);
    }
    __syncthreads();
    #pragma unroll
    for (int kk = 0; kk < BKg; kk += 32) {
      const int sk = kk ? s1 : s0;
      bf16x8 af[4], bfr[4];
      #pragma unroll
      for (int i = 0; i < 4; ++i)
        af[i] = *(const bf16x8*)&As[(wr * 64 + i * 16 + l16) * BKg + sk];
      #pragma unroll
      for (int i = 0; i < 4; ++i)
        bfr[i] = *(const bf16x8*)&Bs[(wc * 64 + i * 16 + l16) * BKg + sk];
      #pragma unroll
      for (int mi = 0; mi < 4; ++mi)
        #pragma unroll
        for (int ni = 0; ni < 4; ++ni)
          acc[mi][ni] = mfma(af[mi], bfr[ni], acc[mi][ni]);
    }
    __syncthreads();
  }

  bf16* Cb = (bf16*)C;
  float* Cf = (float*)C;
  #pragma unroll
  for (int ni = 0; ni < 4; ++ni) {
    const int col = n0 + wc * 64 + ni * 16 + l16;
    const float bv = isbf ? (float)((const bf16*)bias)[col] : ((const float*)bias)[col];
    #pragma unroll
    for (int mi = 0; mi < 4; ++mi)
      #pragma unroll
      for (int r = 0; r < 4; ++r) {
        const int row = m0 + wr * 64 + mi * 16 + quad * 4 + r;
        const float v = acc[mi][ni][r] + bv;
        if (isbf) Cb[(size_t)row * D + col] = (bf16)v;
        else      Cf[(size_t)row * D + col] = v;
      }
  }
}

// ---------- fused causal flash attention v5: S^T, exp2 domain, MFMA row-sum ----------
// S^T = K·Q^T per 16-key block: C row=quad*4+r -> key, col=l16 -> q-row.
// Scores arrive in log2 units (Q pre-scaled by 0.125*log2e in the QKV GEMM).
// Per-lane softmax max state is a SCALAR (one q-row per lane). Row-sum computed
// on the MFMA pipe via a ones-B-fragment accumulator (o_sum); its C-layout row
// (quad*4+r) matches o_acc, so the epilogue needs no shuffles. Rescale pass is
// skipped via defer-max (THR=8 -> P bounded by 256, safe in bf16/f32).
__global__ __launch_bounds__(256) void attn_k(bf16* QO,
                                              const bf16* __restrict__ K,
                                              const bf16* __restrict__ VT) {
  __shared__ __align__(16) bf16 Ks[64 * DH];       // swizzled [key][d]
  __shared__ __align__(16) bf16 Vt[DH * 64];       // swizzled [d][key]
  __shared__ __align__(16) bf16 Ps[4][16 * PST];   // per-wave P [q][key], padded

  const int bx = blockIdx.x;
  const int qt = (L / 64 - 1) - (bx >> 6);
  const int bh = bx & 63;
  const int b = bh >> 4, h = bh & 15;
  const int tid = threadIdx.x, wave = tid >> 6, lane = tid & 63;
  const int quad = lane >> 4, l16 = lane & 15;
  const int srow = lane >> 3;
  const int scol = ((lane ^ srow) & 7) * 8;
  const int l7 = l16 & 7;
  const int s0 = ((quad ^ l7) * 8);
  const int s1 = s0 ^ 32;

  bf16* Qb = QO + (size_t)b * L * D + h * DH;
  const bf16* Kb = K + (size_t)b * L * D + h * DH;
  const bf16* VTg = VT + (size_t)bh * DH * L;

  // Q B-frags; 0.125*log2(e) scale already folded in by the QKV GEMM
  const int qrow = qt * 64 + wave * 16 + l16;
  const bf16x8 qf0 = *(const bf16x8*)(Qb + (size_t)qrow * D + quad * 8);
  const bf16x8 qf1 = *(const bf16x8*)(Qb + (size_t)qrow * D + 32 + quad * 8);

  bf16x8 ones;
  #pragma unroll
  for (int j = 0; j < 8; ++j) ones[j] = (bf16)1.0f;

  float m_run = -INFINITY;                // log2-domain max for q-row l16 (per lane)
  f32x4 o_acc[4] = {};                    // PV C-layout: row=quad*4+r -> q
  f32x4 o_sum = {};                       // MFMA row-sum (P @ ones), same layout

  for (int kt = 0; kt <= qt; ++kt) {
    for (int c = wave; c < 8; c += 4) {
      load_lds16(Kb  + (size_t)(kt * 64 + c * 8 + srow) * D + scol, &Ks[c * 512]);
      load_lds16(VTg + (size_t)(c * 8 + srow) * L + kt * 64 + scol, &Vt[c * 512]);
    }
    __syncthreads();

    // S^T = K @ Q^T: A=K-frag, B=Q-frag. s[nb][r] = S[key=nb*16+quad*4+r][q=l16]
    f32x4 s[4];
    #pragma unroll
    for (int nb = 0; nb < 4; ++nb) {
      bf16x8 k0 = *(const bf16x8*)&Ks[(nb * 16 + l16) * DH + s0];
      bf16x8 k1 = *(const bf16x8*)&Ks[(nb * 16 + l16) * DH + s1];
      f32x4 a = {};
      a = mfma(k0, qf0, a);
      a = mfma(k1, qf1, a);
      s[nb] = a;
    }

    if (kt == qt) { // diagonal causal mask: key > qrow (both 64-tile local)
      const int qloc = wave * 16 + l16;
      #pragma unroll
      for (int nb = 0; nb < 4; ++nb)
        #pragma unroll
        for (int r = 0; r < 4; ++r)
          if (nb * 16 + quad * 4 + r > qloc) s[nb][r] = -1e30f;
    }

    // tile max (max3-friendly grouping), then cross-quad reduce
    float mx = -INFINITY;
    #pragma unroll
    for (int nb = 0; nb < 4; ++nb) {
      const float a = fmaxf(fmaxf(s[nb][0], s[nb][1]), fmaxf(s[nb][2], s[nb][3]));
      mx = fmaxf(mx, a);
    }
    mx = fmaxf(mx, __shfl_xor(mx, 16, 64));
    mx = fmaxf(mx, __shfl_xor(mx, 32, 64));

    // defer-max: rescale only when the running max grows by more than THR=8
    // (log2 domain -> P bounded by 2^8=256; wave-uniform branch via __all)
    if (!__all(mx <= m_run + 8.f)) {
      const float mn = fmaxf(m_run, mx);
      const float alpha = __builtin_amdgcn_exp2f(m_run - mn);
      m_run = mn;
      #pragma unroll
      for (int r = 0; r < 4; ++r) {
        const float ar = __shfl(alpha, quad * 4 + r, 64);
        o_sum[r] *= ar;
        #pragma unroll
        for (int db = 0; db < 4; ++db) o_acc[db][r] *= ar;
      }
    }

    // P = 2^(s - m_run), packed b64 writes in [q][key] layout
    bf16* Pw = &Ps[wave][0];
    #pragma unroll
    for (int nb = 0; nb < 4; ++nb) {
      bf16x4 pk;
      #pragma unroll
      for (int r = 0; r < 4; ++r)
        pk[r] = (bf16)__builtin_amdgcn_exp2f(s[nb][r] - m_run);
      *(bf16x4*)&Pw[l16 * PST + nb * 16 + quad * 4] = pk;
    }

    // O += P @ V ; row-sum += P @ 1 (MFMA pipe does the softmax denominator)
    bf16x8 p0 = *(const bf16x8*)&Pw[l16 * PST + quad * 8];
    bf16x8 p1 = *(const bf16x8*)&Pw[l16 * PST + 32 + quad * 8];
    o_sum = mfma(p0, ones, o_sum);
    o_sum = mfma(p1, ones, o_sum);
    #pragma unroll
    for (int db = 0; db < 4; ++db) {
      bf16x8 v0 = *(const bf16x8*)&Vt[(db * 16 + l16) * 64 + s0];
      bf16x8 v1 = *(const bf16x8*)&Vt[(db * 16 + l16) * 64 + s1];
      o_acc[db] = mfma(p0, v0, o_acc[db]);
      o_acc[db] = mfma(p1, v1, o_acc[db]);
    }
    __syncthreads(); // protect Ks/Vt before next tile's staging
  }

  #pragma unroll
  for (int r = 0; r < 4; ++r) {
    const float inv = 1.f / o_sum[r];   // shuffle-free: o_sum row == o_acc row
    const int row = qt * 64 + wave * 16 + quad * 4 + r;
    #pragma unroll
    for (int db = 0; db < 4; ++db)
      Qb[(size_t)row * D + db * 16 + l16] = (bf16)(o_acc[db][r] * inv);
  }
}

extern "C" void kernel_launch(void* const* d_in, const int* in_sizes, int n_in,
                              void* d_out, int out_size, void* d_ws, size_t ws_size,
                              hipStream_t stream) {
  const void* x  = d_in[0];
  const void* Wq = d_in[1];
  const void* bq = d_in[2];
  const void* Wk = d_in[3];
  const void* bk = d_in[4];
  const void* Wv = d_in[5];
  const void* bv = d_in[6];
  const void* Wo = d_in[7];
  const void* bo = d_in[8];
  // d_in[9] = causal mask, analytic

  int* flag = (int*)d_ws;
  char* p = (char*)d_ws + 4096;
  bf16* xc  = (bf16*)p;                 p += (size_t)BL * D * 2;
  bf16* WqT = (bf16*)p;                 p += (size_t)D * D * 2; // WqT/WkT/WvT/WoT
  bf16* WkT = (bf16*)p;                 p += (size_t)D * D * 2; // contiguous =
  bf16* WvT = (bf16*)p;                 p += (size_t)D * D * 2; // stacked [4096][1024]
  bf16* WoT = (bf16*)p;                 p += (size_t)D * D * 2;
  bf16* Qb  = (bf16*)p;                 p += (size_t)BL * D * 2; // O aliases Q
  bf16* Kb  = (bf16*)p;                 p += (size_t)BL * D * 2;
  bf16* Vb  = (bf16*)p;
  bf16* VTb = xc; // xc dead after QKV GEMM; reuse for V^T

  sniff_k<<<1, 64, 0, stream>>>((const unsigned short*)x, flag);

  cvt_x_k<<<1024, 256, 0, stream>>>(x, xc, flag, BL * D);
  wtrans_cvt4_k<<<dim3(32, 32, 4), 256, 0, stream>>>(Wq, Wk, Wv, Wo, WqT, flag);

  qkv_gemm_k<<<dim3(GM / 128, 3072 / 128), 256, 0, stream>>>(
      xc, WqT, bq, bk, bv, Qb, Kb, Vb, flag);

  vtrans_k<<<dim3(L / 64, B * H), 256, 0, stream>>>(Vb, VTb);

  attn_k<<<dim3((L / 64) * B * H), 256, 0, stream>>>(Qb, Kb, VTb);

  gemm_bt_k<<<dim3(GM / 128, D / 128), 256, 0, stream>>>(Qb, WoT, bo, d_out, flag);
}